// Round 23
// baseline (167.065 us; speedup 1.0000x reference)
//
#include <hip/hip_runtime.h>
#include <hip/hip_fp16.h>
#include <math.h>

#define N_NODES 262144
#define N_EDGES 4194304
#define N_GRAPHS 1024
#define NBK 512                  // dst buckets (512 nodes each)
#define CAP 8960                 // per-bucket capacity (mean 8192 + 8.5 sigma)
#define SCAP 2560                // per-sub-bucket (128 nodes; mean 2048 + 11 sigma)
#define ABLK 512                 // fusedAB blocks (2/CU; 1024 thr -> 32 waves/CU)
#define AEPB (N_EDGES / ABLK)    // 8192 edges per block; run = 16 edges = 64B

typedef _Float16 half2v __attribute__((ext_vector_type(2)));
__device__ inline half2v u2h(unsigned u) { union { unsigned u; half2v h; } c; c.u = u; return c.h; }
__device__ inline unsigned packh2(float a, float b) {
    union { __half2 h; unsigned u; } c; c.h = __floats2half2_rn(a, b); return c.u;
}

// ---------------------------------------------------------------------------
// fusedAB (R21-verified): 1024 threads/block, 512 blocks -> 32 waves/CU.
// Dual-sub-histogram + range reservation + line-dense 16-edge-run scatter.
// ---------------------------------------------------------------------------
__global__ __launch_bounds__(1024) void fusedAB(
    const int* __restrict__ ei, const float* __restrict__ x,
    const float* __restrict__ pos, int* __restrict__ gcur,
    int* __restrict__ binned, uint4* __restrict__ px16,
    float* __restrict__ pooled)
{
    __shared__ int lh2[2][NBK];
    int t = threadIdx.x, b = blockIdx.x;
    int half = (t >> 6) & 1;     // wave parity -> private sub-histogram

    if (t < 512) {
        int n = b * 512 + t;
        float4 v = ((const float4*)x)[n];
        float p0 = pos[3 * n], p1 = pos[3 * n + 1], p2 = pos[3 * n + 2];
        uint4 r;
        r.x = packh2(v.x, v.y);
        r.y = packh2(v.z, v.w);
        r.z = packh2(p0, p1);
        r.w = packh2(p2, 0.0f);
        px16[n] = r;
        lh2[0][t] = 0;
        lh2[1][t] = 0;
    }
    int pid = b * 1024 + t;
    if (pid < 1025 * 32) pooled[pid] = 0.0f;
    __syncthreads();

    const int4* dsts = (const int4*)(ei + N_EDGES + b * AEPB);
    #pragma unroll
    for (int i = 0; i < AEPB / 4096; ++i) {
        int4 d4 = dsts[i * 1024 + t];
        atomicAdd(&lh2[half][d4.x >> 9], 1);
        atomicAdd(&lh2[half][d4.y >> 9], 1);
        atomicAdd(&lh2[half][d4.z >> 9], 1);
        atomicAdd(&lh2[half][d4.w >> 9], 1);
    }
    __syncthreads();
    if (t < 512) {
        int tot = lh2[0][t] + lh2[1][t];
        lh2[0][t] = atomicAdd(&gcur[t * 16], tot);   // reserved base cursor
    }
    __syncthreads();
    const int4* srcp = (const int4*)(ei + b * AEPB);
    #pragma unroll
    for (int i = 0; i < AEPB / 4096; ++i) {
        int4 s4 = srcp[i * 1024 + t];
        int4 d4 = dsts[i * 1024 + t];
        int slot;
        slot = atomicAdd(&lh2[0][d4.x >> 9], 1);
        if (slot < CAP) binned[(size_t)(d4.x >> 9) * CAP + slot] = s4.x | ((d4.x & 511) << 18);
        slot = atomicAdd(&lh2[0][d4.y >> 9], 1);
        if (slot < CAP) binned[(size_t)(d4.y >> 9) * CAP + slot] = s4.y | ((d4.y & 511) << 18);
        slot = atomicAdd(&lh2[0][d4.z >> 9], 1);
        if (slot < CAP) binned[(size_t)(d4.z >> 9) * CAP + slot] = s4.z | ((d4.z & 511) << 18);
        slot = atomicAdd(&lh2[0][d4.w >> 9], 1);
        if (slot < CAP) binned[(size_t)(d4.w >> 9) * CAP + slot] = s4.w | ((d4.w & 511) << 18);
    }
}

// ---------------------------------------------------------------------------
// bucket_fused (R21 + ACROSS-NODE prologue pipeline): while node nn's j-loop
// runs, node nn+1's meta reads + first-chunk srcs + px16 gathers are already
// in flight — hides the per-node cold-start gather latency that the
// within-node prefetch (R17) could not touch at median deg~16.
// ---------------------------------------------------------------------------
__global__ __launch_bounds__(256) void bucket_fused(
    const int* __restrict__ gcur, const int* __restrict__ binned,
    const uint4* __restrict__ px16,
    const float* __restrict__ W1, const float* __restrict__ b1,
    const float* __restrict__ W2, const float* __restrict__ b2,
    const float* __restrict__ Wp, const float* __restrict__ bp,
    const int* __restrict__ batch,
    float* __restrict__ out_s, float* __restrict__ pooled)
{
    __shared__ int sbuf[SCAP];
    __shared__ int ldeg[128], lstart[128], lcur[128], lperm[128], bloc[128];
    __shared__ int wsum[2];
    __shared__ int scnt;
    __shared__ uint4 sepk[16][17];
    __shared__ float smh[16][20];
    __shared__ float lpool[4][33];

    int t = threadIdx.x;
    int k = blockIdx.x & (NBK - 1);      // bucket
    int sub = blockIdx.x >> 9;           // sub-bucket 0..3
    int ebase = k * CAP;
    int cnt = gcur[k * 16];
    if (cnt > CAP) cnt = CAP;

    if (t < 128) {
        ldeg[t] = 0;
        bloc[t] = batch[(k << 9) + (sub << 7) + t];
    }
    if (t < 4 * 33) ((float*)lpool)[t] = 0.0f;
    if (t == 0) scnt = 0;
    __syncthreads();

    // 1) filter my 128 nodes' edges into sbuf + degree histogram
    for (int i = t; i < cnt; i += 256) {
        int pk = binned[ebase + i];
        if (((pk >> 25) & 3) == sub) {
            atomicAdd(&ldeg[(pk >> 18) & 127], 1);
            int sl = atomicAdd(&scnt, 1);
            if (sl < SCAP) sbuf[sl] = pk;
        }
    }
    __syncthreads();
    int sc = scnt < SCAP ? scnt : SCAP;
    int dgv = (t < 128) ? ldeg[t] : 0;

    // 2) inclusive scan over 128 degrees (2 waves, shfl + fixup)
    int lane = t & 63, wid = t >> 6;
    int sv = dgv;
    #pragma unroll
    for (int o = 1; o < 64; o <<= 1) {
        int u = __shfl_up(sv, o);
        if (lane >= o) sv += u;
    }
    if (lane == 63 && wid < 2) wsum[wid] = sv;
    __syncthreads();
    int excl = sv + ((wid == 1) ? wsum[0] : 0) - dgv;
    if (t < 128) { lstart[t] = excl; lcur[t] = excl; }

    // 3) deg-rank within each 16-node window (ties by index)
    if (t < 128) {
        int wbase = t & ~15;
        int rank = 0;
        #pragma unroll
        for (int j = 0; j < 16; ++j) {
            int dj = ldeg[wbase + j];
            rank += (dj < dgv) || (dj == dgv && (wbase + j) < t);
        }
        lperm[wbase + rank] = t;
    }
    __syncthreads();

    // 4) in-place node-group permute via register staging (static indices)
    int regpk[10];
    #pragma unroll
    for (int c = 0; c < 10; ++c) {
        int i = t + c * 256;
        regpk[c] = (i < sc) ? sbuf[i] : -1;
    }
    __syncthreads();
    #pragma unroll
    for (int c = 0; c < 10; ++c) {
        int pk = regpk[c];
        if (pk >= 0) {
            int sl = atomicAdd(&lcur[(pk >> 18) & 127], 1);
            sbuf[sl] = pk & 0x3FFFF;   // src id, grouped by local node
        }
    }
    __syncthreads();

    // ---- MLP gather phase (R17-verified math); across-node pipelined ----
    int g = t & 15, grp = t >> 4;

    float w1c0 = W1[0 * 16 + g], w1c1 = W1[1 * 16 + g];
    float w1c2 = W1[2 * 16 + g], w1c3 = W1[3 * 16 + g];
    half2v wh45, wh67;
    wh45[0] = (_Float16)W1[4 * 16 + g];
    wh45[1] = (_Float16)W1[5 * 16 + g];
    wh67[0] = (_Float16)W1[6 * 16 + g];
    wh67[1] = (_Float16)W1[7 * 16 + g];
    float w1c8 = W1[8 * 16 + g];
    float b1g = b1[g], b2g = b2[g];
    float w2col[16];
    #pragma unroll
    for (int i = 0; i < 16; ++i) w2col[i] = W2[i * 16 + g];
    float wp0 = Wp[2 * g], wp1 = Wp[2 * g + 1];
    int sg0 = bloc[0];
    int nodebase = (k << 9) + (sub << 7);

    // prologue for node-round 0
    int wCur = lperm[grp];
    int baseCur = lstart[wCur], dgCur = ldeg[wCur];
    uint4 rnCur = px16[nodebase + wCur];
    int sCcur = (g < dgCur) ? sbuf[baseCur + g] : 0;
    uint4 rCcur = px16[sCcur];
    int sNcur = (16 + g < dgCur) ? sbuf[baseCur + 16 + g] : sCcur;

    for (int nn = 0; nn < 8; ++nn) {
        // issue next node's prologue loads (in flight during this node's work)
        int wNxt = wCur, baseNxt = baseCur, dgNxt = dgCur, sCnxt = sCcur, sNnxt = sNcur;
        uint4 rnNxt = rnCur, rCnxt = rCcur;
        if (nn < 7) {
            wNxt = lperm[(nn + 1) * 16 + grp];
            baseNxt = lstart[wNxt];
            dgNxt = ldeg[wNxt];
            rnNxt = px16[nodebase + wNxt];
            sCnxt = (g < dgNxt) ? sbuf[baseNxt + g] : 0;
            rCnxt = px16[sCnxt];
            sNnxt = (16 + g < dgNxt) ? sbuf[baseNxt + 16 + g] : sCnxt;
        }

        int w = wCur, base = baseCur, dg = dgCur;
        int n = nodebase + w;
        uint4 rn = rnCur;
        float2 f01 = __half22float2(*(__half2*)&rn.x);
        float2 f23 = __half22float2(*(__half2*)&rn.y);
        float2 f45 = __half22float2(*(__half2*)&rn.z);
        float2 f67 = __half22float2(*(__half2*)&rn.w);
        float pnx = f45.x, pny = f45.y, pnz = f67.x;
        float pre = b1g + f01.x * w1c0 + f01.y * w1c1 + f23.x * w1c2 + f23.y * w1c3;

        float sumH = 0.0f;
        uint4 rC = rCcur;
        int sN = sNcur;

        for (int k0 = 0; k0 < dg; k0 += 16) {
            int rem = dg - k0;
            int cc = rem < 16 ? rem : 16;
            if (g < cc) {
                float2 e45 = __half22float2(*(__half2*)&rC.z);
                float2 e67 = __half22float2(*(__half2*)&rC.w);
                float dx = e45.x - pnx, dy = e45.y - pny, dz = e67.x - pnz;
                float dist = sqrtf(dx * dx + dy * dy + dz * dz);
                sepk[grp][g] = make_uint4(rC.x, rC.y, __float_as_uint(dist), 0u);
            }
            uint4 rNext = px16[sN];
            int sNN = (k0 + 32 + g < dg) ? sbuf[base + k0 + 32 + g] : sN;
            int j = 0;
            for (; j + 1 < cc; j += 2) {
                uint4 A = sepk[grp][j];
                uint4 B = sepk[grp][j + 1];
                float a = fmaf(__uint_as_float(A.z), w1c8, pre);
                a = __builtin_amdgcn_fdot2(u2h(A.x), wh45, a, false);
                a = __builtin_amdgcn_fdot2(u2h(A.y), wh67, a, false);
                sumH += a * __builtin_amdgcn_rcpf(1.0f + __expf(-a));
                float bb = fmaf(__uint_as_float(B.z), w1c8, pre);
                bb = __builtin_amdgcn_fdot2(u2h(B.x), wh45, bb, false);
                bb = __builtin_amdgcn_fdot2(u2h(B.y), wh67, bb, false);
                sumH += bb * __builtin_amdgcn_rcpf(1.0f + __expf(-bb));
            }
            if (j < cc) {
                uint4 A = sepk[grp][j];
                float a = fmaf(__uint_as_float(A.z), w1c8, pre);
                a = __builtin_amdgcn_fdot2(u2h(A.x), wh45, a, false);
                a = __builtin_amdgcn_fdot2(u2h(A.y), wh67, a, false);
                sumH += a * __builtin_amdgcn_rcpf(1.0f + __expf(-a));
            }
            rC = rNext;
            sN = sNN;
        }

        // LDS-transpose epilogue: lane g applies W2 column g
        smh[grp][g] = sumH;
        float4 s0v = *(const float4*)&smh[grp][0];
        float4 s1v = *(const float4*)&smh[grp][4];
        float4 s2v = *(const float4*)&smh[grp][8];
        float4 s3v = *(const float4*)&smh[grp][12];
        float red = s0v.x * w2col[0] + s0v.y * w2col[1] + s0v.z * w2col[2] + s0v.w * w2col[3]
                  + s1v.x * w2col[4] + s1v.y * w2col[5] + s1v.z * w2col[6] + s1v.w * w2col[7]
                  + s2v.x * w2col[8] + s2v.y * w2col[9] + s2v.z * w2col[10] + s2v.w * w2col[11]
                  + s3v.x * w2col[12] + s3v.y * w2col[13] + s3v.z * w2col[14] + s3v.w * w2col[15];

        float fdg = (float)dg;
        float inv = 1.0f / fmaxf(fdg, 1.0f);
        float h = fmaxf((red + fdg * b2g) * inv, 0.0f);

        float c0 = h * wp0, c1 = h * wp1;
        #pragma unroll
        for (int mset = 8; mset > 0; mset >>= 1) {
            c0 += __shfl_xor(c0, mset);
            c1 += __shfl_xor(c1, mset);
        }
        float l0 = c0 + bp[0], l1 = c1 + bp[1];
        float mx = fmaxf(l0, l1);
        float e0s = __expf(l0 - mx), e1s = __expf(l1 - mx);
        float isum = 1.0f / (e0s + e1s);
        float s0 = e0s * isum, s1 = e1s * isum;

        if (g == 0) ((float2*)out_s)[n] = make_float2(s0, s1);

        int gid = bloc[w];
        int idx = gid - sg0;
        float p0 = s0 * h, p1 = s1 * h;
        if (idx < 4) {
            atomicAdd(&lpool[idx][g], p0);
            atomicAdd(&lpool[idx][16 + g], p1);
        } else {  // pathological many-tiny-graphs fallback
            atomicAdd(&pooled[gid * 32 + g], p0);
            atomicAdd(&pooled[gid * 32 + 16 + g], p1);
        }

        wCur = wNxt; baseCur = baseNxt; dgCur = dgNxt;
        rnCur = rnNxt; rCcur = rCnxt; sCcur = sCnxt; sNcur = sNnxt;
    }
    __syncthreads();

    // flush sub-bucket pooling rows
    if (t < 128) {
        int gi = t >> 5, c = t & 31;
        int ngr = bloc[127] - sg0 + 1;
        if (gi < ngr && gi < 4) {
            float v = lpool[gi][c];
            if (v != 0.0f) atomicAdd(&pooled[(sg0 + gi) * 32 + c], v);
        }
    }
}

// ---------------------------------------------------------------------------
// z = pooled.reshape(G,32) @ Wz + bz
// ---------------------------------------------------------------------------
__global__ __launch_bounds__(256) void z_kernel(const float* __restrict__ pooled,
                                                const float* __restrict__ Wz,
                                                const float* __restrict__ bz,
                                                float* __restrict__ out_z) {
    int idx = blockIdx.x * 256 + threadIdx.x;
    if (idx >= N_GRAPHS * 8) return;
    int gph = idx >> 3, o = idx & 7;
    float a = bz[o];
    const float* pp = pooled + (size_t)gph * 32;
    #pragma unroll
    for (int j = 0; j < 32; ++j) a = fmaf(pp[j], Wz[j * 8 + o], a);
    out_z[idx] = a;
}

extern "C" void kernel_launch(void* const* d_in, const int* in_sizes, int n_in,
                              void* d_out, int out_size, void* d_ws, size_t ws_size,
                              hipStream_t stream) {
    const float* x    = (const float*)d_in[0];
    const float* pos  = (const float*)d_in[1];
    const float* W1   = (const float*)d_in[2];
    const float* b1   = (const float*)d_in[3];
    const float* W2   = (const float*)d_in[4];
    const float* b2   = (const float*)d_in[5];
    const float* Wp   = (const float*)d_in[6];
    const float* bp   = (const float*)d_in[7];
    const float* Wz   = (const float*)d_in[8];
    const float* bz   = (const float*)d_in[9];
    const int*   ei   = (const int*)d_in[10];
    const int*   batch= (const int*)d_in[11];
    float* out = (float*)d_out;
    float* out_z = out;                   // [1024*8]
    float* out_s = out + N_GRAPHS * 8;    // [262144*2]

    // ws (ints): gcur[NBK*16] | binned[NBK*CAP] | pooled[1025*32] | px16[N uint4]
    int* gcur     = (int*)d_ws;
    int* binned   = gcur + NBK * 16;
    float* pooled = (float*)(binned + (size_t)NBK * CAP);
    uint4* px16   = (uint4*)(pooled + 1025 * 32);          // 16B-aligned

    hipMemsetAsync(gcur, 0, NBK * 16 * sizeof(int), stream);
    fusedAB<<<ABLK, 1024, 0, stream>>>(ei, x, pos, gcur, binned, px16, pooled);
    bucket_fused<<<NBK * 4, 256, 0, stream>>>(gcur, binned, px16, W1, b1, W2, b2,
                                              Wp, bp, batch, out_s, pooled);
    z_kernel<<<32, 256, 0, stream>>>(pooled, Wz, bz, out_z);
}

// Round 24
// 143.278 us; speedup vs baseline: 1.1660x; 1.1660x over previous
//
#include <hip/hip_runtime.h>
#include <hip/hip_fp16.h>
#include <math.h>

#define N_NODES 262144
#define N_EDGES 4194304
#define N_GRAPHS 1024
#define NBK 512                  // dst buckets (512 nodes each)
#define CAP 8960                 // per-bucket capacity (mean 8192 + 8.5 sigma)
#define SCAP 2560                // per-sub-bucket (128 nodes; mean 2048 + 11 sigma)
#define ABLK 512                 // fusedAB blocks (2/CU; 1024 thr -> 32 waves/CU)
#define AEPB (N_EDGES / ABLK)    // 8192 edges per block; run = 16 edges = 64B

typedef _Float16 half2v __attribute__((ext_vector_type(2)));
__device__ inline half2v u2h(unsigned u) { union { unsigned u; half2v h; } c; c.u = u; return c.h; }
__device__ inline unsigned packh2(float a, float b) {
    union { __half2 h; unsigned u; } c; c.h = __floats2half2_rn(a, b); return c.u;
}

// ---------------------------------------------------------------------------
// fusedAB (R21-verified): 1024 threads/block, 512 blocks -> 32 waves/CU.
// Dual-sub-histogram + range reservation + line-dense 16-edge-run scatter.
// ---------------------------------------------------------------------------
__global__ __launch_bounds__(1024) void fusedAB(
    const int* __restrict__ ei, const float* __restrict__ x,
    const float* __restrict__ pos, int* __restrict__ gcur,
    int* __restrict__ binned, uint4* __restrict__ px16,
    float* __restrict__ pooled)
{
    __shared__ int lh2[2][NBK];
    int t = threadIdx.x, b = blockIdx.x;
    int half = (t >> 6) & 1;     // wave parity -> private sub-histogram

    if (t < 512) {
        int n = b * 512 + t;
        float4 v = ((const float4*)x)[n];
        float p0 = pos[3 * n], p1 = pos[3 * n + 1], p2 = pos[3 * n + 2];
        uint4 r;
        r.x = packh2(v.x, v.y);
        r.y = packh2(v.z, v.w);
        r.z = packh2(p0, p1);
        r.w = packh2(p2, 0.0f);
        px16[n] = r;
        lh2[0][t] = 0;
        lh2[1][t] = 0;
    }
    int pid = b * 1024 + t;
    if (pid < 1025 * 32) pooled[pid] = 0.0f;
    __syncthreads();

    const int4* dsts = (const int4*)(ei + N_EDGES + b * AEPB);
    #pragma unroll
    for (int i = 0; i < AEPB / 4096; ++i) {
        int4 d4 = dsts[i * 1024 + t];
        atomicAdd(&lh2[half][d4.x >> 9], 1);
        atomicAdd(&lh2[half][d4.y >> 9], 1);
        atomicAdd(&lh2[half][d4.z >> 9], 1);
        atomicAdd(&lh2[half][d4.w >> 9], 1);
    }
    __syncthreads();
    if (t < 512) {
        int tot = lh2[0][t] + lh2[1][t];
        lh2[0][t] = atomicAdd(&gcur[t * 16], tot);   // reserved base cursor
    }
    __syncthreads();
    const int4* srcp = (const int4*)(ei + b * AEPB);
    #pragma unroll
    for (int i = 0; i < AEPB / 4096; ++i) {
        int4 s4 = srcp[i * 1024 + t];
        int4 d4 = dsts[i * 1024 + t];
        int slot;
        slot = atomicAdd(&lh2[0][d4.x >> 9], 1);
        if (slot < CAP) binned[(size_t)(d4.x >> 9) * CAP + slot] = s4.x | ((d4.x & 511) << 18);
        slot = atomicAdd(&lh2[0][d4.y >> 9], 1);
        if (slot < CAP) binned[(size_t)(d4.y >> 9) * CAP + slot] = s4.y | ((d4.y & 511) << 18);
        slot = atomicAdd(&lh2[0][d4.z >> 9], 1);
        if (slot < CAP) binned[(size_t)(d4.z >> 9) * CAP + slot] = s4.z | ((d4.z & 511) << 18);
        slot = atomicAdd(&lh2[0][d4.w >> 9], 1);
        if (slot < CAP) binned[(size_t)(d4.w >> 9) * CAP + slot] = s4.w | ((d4.w & 511) << 18);
    }
}

// ---------------------------------------------------------------------------
// bucket_fused (R19/R21-verified): 4 sub-blocks per bucket, 256 thr,
// ~19KB LDS -> 8 blocks/CU. Filter to LDS, node-group sort in place,
// window deg-rank, MLP gather (R17 math), fused pooling.
// ---------------------------------------------------------------------------
__global__ __launch_bounds__(256) void bucket_fused(
    const int* __restrict__ gcur, const int* __restrict__ binned,
    const uint4* __restrict__ px16,
    const float* __restrict__ W1, const float* __restrict__ b1,
    const float* __restrict__ W2, const float* __restrict__ b2,
    const float* __restrict__ Wp, const float* __restrict__ bp,
    const int* __restrict__ batch,
    float* __restrict__ out_s, float* __restrict__ pooled)
{
    __shared__ int sbuf[SCAP];
    __shared__ int ldeg[128], lstart[128], lcur[128], lperm[128], bloc[128];
    __shared__ int wsum[2];
    __shared__ int scnt;
    __shared__ uint4 sepk[16][17];
    __shared__ float smh[16][20];
    __shared__ float lpool[4][33];

    int t = threadIdx.x;
    int k = blockIdx.x & (NBK - 1);      // bucket
    int sub = blockIdx.x >> 9;           // sub-bucket 0..3
    int ebase = k * CAP;
    int cnt = gcur[k * 16];
    if (cnt > CAP) cnt = CAP;

    if (t < 128) {
        ldeg[t] = 0;
        bloc[t] = batch[(k << 9) + (sub << 7) + t];
    }
    if (t < 4 * 33) ((float*)lpool)[t] = 0.0f;
    if (t == 0) scnt = 0;
    __syncthreads();

    // 1) filter my 128 nodes' edges into sbuf + degree histogram
    for (int i = t; i < cnt; i += 256) {
        int pk = binned[ebase + i];
        if (((pk >> 25) & 3) == sub) {
            atomicAdd(&ldeg[(pk >> 18) & 127], 1);
            int sl = atomicAdd(&scnt, 1);
            if (sl < SCAP) sbuf[sl] = pk;
        }
    }
    __syncthreads();
    int sc = scnt < SCAP ? scnt : SCAP;
    int dgv = (t < 128) ? ldeg[t] : 0;

    // 2) inclusive scan over 128 degrees (2 waves, shfl + fixup)
    int lane = t & 63, wid = t >> 6;
    int sv = dgv;
    #pragma unroll
    for (int o = 1; o < 64; o <<= 1) {
        int u = __shfl_up(sv, o);
        if (lane >= o) sv += u;
    }
    if (lane == 63 && wid < 2) wsum[wid] = sv;
    __syncthreads();
    int excl = sv + ((wid == 1) ? wsum[0] : 0) - dgv;
    if (t < 128) { lstart[t] = excl; lcur[t] = excl; }

    // 3) deg-rank within each 16-node window (ties by index)
    if (t < 128) {
        int wbase = t & ~15;
        int rank = 0;
        #pragma unroll
        for (int j = 0; j < 16; ++j) {
            int dj = ldeg[wbase + j];
            rank += (dj < dgv) || (dj == dgv && (wbase + j) < t);
        }
        lperm[wbase + rank] = t;
    }
    __syncthreads();

    // 4) in-place node-group permute via register staging (static indices)
    int regpk[10];
    #pragma unroll
    for (int c = 0; c < 10; ++c) {
        int i = t + c * 256;
        regpk[c] = (i < sc) ? sbuf[i] : -1;
    }
    __syncthreads();
    #pragma unroll
    for (int c = 0; c < 10; ++c) {
        int pk = regpk[c];
        if (pk >= 0) {
            int sl = atomicAdd(&lcur[(pk >> 18) & 127], 1);
            sbuf[sl] = pk & 0x3FFFF;   // src id, grouped by local node
        }
    }
    __syncthreads();

    // ---- MLP gather phase (R17-verified math); 16 groups x 8 node-rounds ----
    int g = t & 15, grp = t >> 4;

    float w1c0 = W1[0 * 16 + g], w1c1 = W1[1 * 16 + g];
    float w1c2 = W1[2 * 16 + g], w1c3 = W1[3 * 16 + g];
    half2v wh45, wh67;
    wh45[0] = (_Float16)W1[4 * 16 + g];
    wh45[1] = (_Float16)W1[5 * 16 + g];
    wh67[0] = (_Float16)W1[6 * 16 + g];
    wh67[1] = (_Float16)W1[7 * 16 + g];
    float w1c8 = W1[8 * 16 + g];
    float b1g = b1[g], b2g = b2[g];
    float w2col[16];
    #pragma unroll
    for (int i = 0; i < 16; ++i) w2col[i] = W2[i * 16 + g];
    float wp0 = Wp[2 * g], wp1 = Wp[2 * g + 1];
    int sg0 = bloc[0];

    for (int nn = 0; nn < 8; ++nn) {
        int w = lperm[nn * 16 + grp];    // local node (window deg-rank order)
        int n = (k << 9) + (sub << 7) + w;
        int base = lstart[w];
        int dg = ldeg[w];

        uint4 rn = px16[n];
        float2 f01 = __half22float2(*(__half2*)&rn.x);
        float2 f23 = __half22float2(*(__half2*)&rn.y);
        float2 f45 = __half22float2(*(__half2*)&rn.z);
        float2 f67 = __half22float2(*(__half2*)&rn.w);
        float pnx = f45.x, pny = f45.y, pnz = f67.x;
        float pre = b1g + f01.x * w1c0 + f01.y * w1c1 + f23.x * w1c2 + f23.y * w1c3;

        float sumH = 0.0f;

        int sC = (g < dg) ? sbuf[base + g] : 0;
        uint4 rC = px16[sC];
        int sN = (16 + g < dg) ? sbuf[base + 16 + g] : sC;

        for (int k0 = 0; k0 < dg; k0 += 16) {
            int rem = dg - k0;
            int cc = rem < 16 ? rem : 16;
            if (g < cc) {
                float2 e45 = __half22float2(*(__half2*)&rC.z);
                float2 e67 = __half22float2(*(__half2*)&rC.w);
                float dx = e45.x - pnx, dy = e45.y - pny, dz = e67.x - pnz;
                float dist = sqrtf(dx * dx + dy * dy + dz * dz);
                sepk[grp][g] = make_uint4(rC.x, rC.y, __float_as_uint(dist), 0u);
            }
            uint4 rNext = px16[sN];
            int sNN = (k0 + 32 + g < dg) ? sbuf[base + k0 + 32 + g] : sN;
            int j = 0;
            for (; j + 1 < cc; j += 2) {
                uint4 A = sepk[grp][j];
                uint4 B = sepk[grp][j + 1];
                float a = fmaf(__uint_as_float(A.z), w1c8, pre);
                a = __builtin_amdgcn_fdot2(u2h(A.x), wh45, a, false);
                a = __builtin_amdgcn_fdot2(u2h(A.y), wh67, a, false);
                sumH += a * __builtin_amdgcn_rcpf(1.0f + __expf(-a));
                float bb = fmaf(__uint_as_float(B.z), w1c8, pre);
                bb = __builtin_amdgcn_fdot2(u2h(B.x), wh45, bb, false);
                bb = __builtin_amdgcn_fdot2(u2h(B.y), wh67, bb, false);
                sumH += bb * __builtin_amdgcn_rcpf(1.0f + __expf(-bb));
            }
            if (j < cc) {
                uint4 A = sepk[grp][j];
                float a = fmaf(__uint_as_float(A.z), w1c8, pre);
                a = __builtin_amdgcn_fdot2(u2h(A.x), wh45, a, false);
                a = __builtin_amdgcn_fdot2(u2h(A.y), wh67, a, false);
                sumH += a * __builtin_amdgcn_rcpf(1.0f + __expf(-a));
            }
            rC = rNext;
            sN = sNN;
        }

        // LDS-transpose epilogue: lane g applies W2 column g
        smh[grp][g] = sumH;
        float4 s0v = *(const float4*)&smh[grp][0];
        float4 s1v = *(const float4*)&smh[grp][4];
        float4 s2v = *(const float4*)&smh[grp][8];
        float4 s3v = *(const float4*)&smh[grp][12];
        float red = s0v.x * w2col[0] + s0v.y * w2col[1] + s0v.z * w2col[2] + s0v.w * w2col[3]
                  + s1v.x * w2col[4] + s1v.y * w2col[5] + s1v.z * w2col[6] + s1v.w * w2col[7]
                  + s2v.x * w2col[8] + s2v.y * w2col[9] + s2v.z * w2col[10] + s2v.w * w2col[11]
                  + s3v.x * w2col[12] + s3v.y * w2col[13] + s3v.z * w2col[14] + s3v.w * w2col[15];

        float fdg = (float)dg;
        float inv = 1.0f / fmaxf(fdg, 1.0f);
        float h = fmaxf((red + fdg * b2g) * inv, 0.0f);

        float c0 = h * wp0, c1 = h * wp1;
        #pragma unroll
        for (int mset = 8; mset > 0; mset >>= 1) {
            c0 += __shfl_xor(c0, mset);
            c1 += __shfl_xor(c1, mset);
        }
        float l0 = c0 + bp[0], l1 = c1 + bp[1];
        float mx = fmaxf(l0, l1);
        float e0s = __expf(l0 - mx), e1s = __expf(l1 - mx);
        float isum = 1.0f / (e0s + e1s);
        float s0 = e0s * isum, s1 = e1s * isum;

        if (g == 0) ((float2*)out_s)[n] = make_float2(s0, s1);

        int gid = bloc[w];
        int idx = gid - sg0;
        float p0 = s0 * h, p1 = s1 * h;
        if (idx < 4) {
            atomicAdd(&lpool[idx][g], p0);
            atomicAdd(&lpool[idx][16 + g], p1);
        } else {  // pathological many-tiny-graphs fallback
            atomicAdd(&pooled[gid * 32 + g], p0);
            atomicAdd(&pooled[gid * 32 + 16 + g], p1);
        }
    }
    __syncthreads();

    // flush sub-bucket pooling rows
    if (t < 128) {
        int gi = t >> 5, c = t & 31;
        int ngr = bloc[127] - sg0 + 1;
        if (gi < ngr && gi < 4) {
            float v = lpool[gi][c];
            if (v != 0.0f) atomicAdd(&pooled[(sg0 + gi) * 32 + c], v);
        }
    }
}

// ---------------------------------------------------------------------------
// z = pooled.reshape(G,32) @ Wz + bz
// ---------------------------------------------------------------------------
__global__ __launch_bounds__(256) void z_kernel(const float* __restrict__ pooled,
                                                const float* __restrict__ Wz,
                                                const float* __restrict__ bz,
                                                float* __restrict__ out_z) {
    int idx = blockIdx.x * 256 + threadIdx.x;
    if (idx >= N_GRAPHS * 8) return;
    int gph = idx >> 3, o = idx & 7;
    float a = bz[o];
    const float* pp = pooled + (size_t)gph * 32;
    #pragma unroll
    for (int j = 0; j < 32; ++j) a = fmaf(pp[j], Wz[j * 8 + o], a);
    out_z[idx] = a;
}

extern "C" void kernel_launch(void* const* d_in, const int* in_sizes, int n_in,
                              void* d_out, int out_size, void* d_ws, size_t ws_size,
                              hipStream_t stream) {
    const float* x    = (const float*)d_in[0];
    const float* pos  = (const float*)d_in[1];
    const float* W1   = (const float*)d_in[2];
    const float* b1   = (const float*)d_in[3];
    const float* W2   = (const float*)d_in[4];
    const float* b2   = (const float*)d_in[5];
    const float* Wp   = (const float*)d_in[6];
    const float* bp   = (const float*)d_in[7];
    const float* Wz   = (const float*)d_in[8];
    const float* bz   = (const float*)d_in[9];
    const int*   ei   = (const int*)d_in[10];
    const int*   batch= (const int*)d_in[11];
    float* out = (float*)d_out;
    float* out_z = out;                   // [1024*8]
    float* out_s = out + N_GRAPHS * 8;    // [262144*2]

    // ws (ints): gcur[NBK*16] | binned[NBK*CAP] | pooled[1025*32] | px16[N uint4]
    int* gcur     = (int*)d_ws;
    int* binned   = gcur + NBK * 16;
    float* pooled = (float*)(binned + (size_t)NBK * CAP);
    uint4* px16   = (uint4*)(pooled + 1025 * 32);          // 16B-aligned

    hipMemsetAsync(gcur, 0, NBK * 16 * sizeof(int), stream);
    fusedAB<<<ABLK, 1024, 0, stream>>>(ei, x, pos, gcur, binned, px16, pooled);
    bucket_fused<<<NBK * 4, 256, 0, stream>>>(gcur, binned, px16, W1, b1, W2, b2,
                                              Wp, bp, batch, out_s, pooled);
    z_kernel<<<32, 256, 0, stream>>>(pooled, Wz, bz, out_z);
}